// Round 5
// baseline (176.231 us; speedup 1.0000x reference)
//
#include <hip/hip_runtime.h>
#include <hip/hip_bf16.h>
#include <stdint.h>

typedef _Float16 f16;
typedef _Float16 f16x8 __attribute__((ext_vector_type(8)));
typedef __fp16   fp16x2 __attribute__((ext_vector_type(2)));
typedef float    f32x4 __attribute__((ext_vector_type(4)));
typedef float    f32x16 __attribute__((ext_vector_type(16)));

#define GLDS16(g, l) __builtin_amdgcn_global_load_lds(                        \
    (const __attribute__((address_space(1))) void*)(g),                      \
    (__attribute__((address_space(3))) void*)(l), 16, 0, 0)

constexpr int T  = 2048;
constexpr int B  = 2;
constexpr int H  = 16;
constexpr int DM = 1024;
constexpr int MT = B * T;       // 4096 token rows
constexpr int NQKV = 3 * DM;    // 3072

// ---------------------------------------------------------------- tables
__global__ void k_tables(float* __restrict__ cosT, float* __restrict__ sinT) {
    int idx = blockIdx.x * 256 + threadIdx.x;       // T*32 = 65536
    if (idx >= T * 32) return;
    int t = idx >> 5, f = idx & 31;
    float inv = exp2f(-(float)f * 0.41524101186092034f);
    float ang = (float)t * inv;
    cosT[idx] = cosf(ang);
    sinT[idx] = sinf(ang);
}

// ---------------------------------------------------------------- cast x
__global__ void k_cast_x(const float* __restrict__ x, f16* __restrict__ xh) {
    int i = blockIdx.x * 256 + threadIdx.x;         // per 8 elems
    const float4* p = (const float4*)x;
    float4 a = p[i * 2], b = p[i * 2 + 1];
    f16x8 o = { (f16)a.x, (f16)a.y, (f16)a.z, (f16)a.w,
                (f16)b.x, (f16)b.y, (f16)b.z, (f16)b.w };
    ((f16x8*)xh)[i] = o;
}

// ------------------------------------------------- weight cast+transpose
__global__ void k_wt(const float* __restrict__ Wq, const float* __restrict__ Wk,
                     const float* __restrict__ Wv, const float* __restrict__ Wo,
                     f16* __restrict__ WqkvT, f16* __restrict__ WoT) {
    __shared__ float tile[32][33];
    int z = blockIdx.z;
    const float* src = (z == 0) ? Wq : (z == 1) ? Wk : (z == 2) ? Wv : Wo;
    f16* dst = (z < 3) ? (WqkvT + (size_t)z * DM * DM) : WoT;
    int bx = blockIdx.x * 32, by = blockIdx.y * 32;
    int tx = threadIdx.x, ty = threadIdx.y;
#pragma unroll
    for (int j = 0; j < 4; j++)
        tile[ty + j * 8][tx] = src[(size_t)(by + ty + j * 8) * DM + bx + tx];
    __syncthreads();
#pragma unroll
    for (int j = 0; j < 4; j++)
        dst[(size_t)(bx + ty + j * 8) * DM + by + tx] = (f16)tile[tx][ty + j * 8];
}

// ---------------------------------------------------------------- GEMM
template <bool OUTF32>
__global__ __launch_bounds__(256) void k_gemm(const f16* __restrict__ A,
                                              const f16* __restrict__ Bt,
                                              void* __restrict__ Cv,
                                              const float* __restrict__ bias,
                                              int M, int N, int K) {
    __shared__ f16 sA[128 * 64];
    __shared__ f16 sB[128 * 64];
    const int tid = threadIdx.x, w = tid >> 6, l = tid & 63;
    const int m0 = blockIdx.x * 128, n0 = blockIdx.y * 128;
    const int wm = w >> 1, wn = w & 1;
    const int lrow = tid >> 3;
    const int lch  = tid & 7;
    f32x4 acc[4][4] = {};

    for (int kt = 0; kt < K; kt += 64) {
        __syncthreads();
#pragma unroll
        for (int i = 0; i < 4; i++) {
            int row = i * 32 + lrow;
            int c = lch ^ (row & 7);
            GLDS16(A + (size_t)(m0 + row) * K + kt + c * 8, &sA[i * 2048 + w * 512]);
        }
#pragma unroll
        for (int i = 0; i < 4; i++) {
            int row = i * 32 + lrow;
            int c = lch ^ (row & 7);
            GLDS16(Bt + (size_t)(n0 + row) * K + kt + c * 8, &sB[i * 2048 + w * 512]);
        }
        __syncthreads();
#pragma unroll
        for (int ks = 0; ks < 2; ks++) {
            f16x8 af[4], bf[4];
#pragma unroll
            for (int mi = 0; mi < 4; mi++) {
                int row = wm * 64 + mi * 16 + (l & 15);
                int c = (ks * 4 + (l >> 4)) ^ (row & 7);
                af[mi] = *(const f16x8*)&sA[row * 64 + c * 8];
            }
#pragma unroll
            for (int ni = 0; ni < 4; ni++) {
                int row = wn * 64 + ni * 16 + (l & 15);
                int c = (ks * 4 + (l >> 4)) ^ (row & 7);
                bf[ni] = *(const f16x8*)&sB[row * 64 + c * 8];
            }
#pragma unroll
            for (int ni = 0; ni < 4; ni++)
#pragma unroll
                for (int mi = 0; mi < 4; mi++)
                    acc[mi][ni] = __builtin_amdgcn_mfma_f32_16x16x32_f16(
                        af[mi], bf[ni], acc[mi][ni], 0, 0, 0);
        }
    }
    const int rb = m0 + wm * 64 + ((l >> 4) << 2);
    const int cb = n0 + wn * 64 + (l & 15);
#pragma unroll
    for (int ni = 0; ni < 4; ni++) {
        int col = cb + ni * 16;
        float bz = bias ? bias[col] : 0.f;
#pragma unroll
        for (int mi = 0; mi < 4; mi++) {
#pragma unroll
            for (int r = 0; r < 4; r++) {
                int row = rb + mi * 16 + r;
                float v = acc[mi][ni][r] + bz;
                if (OUTF32) ((float*)Cv)[(size_t)row * N + col] = v;
                else        ((f16*)Cv)[(size_t)row * N + col] = (f16)v;
            }
        }
    }
}

// --------------------------------------------- RoPE + bias + head permute
// Q pre-scale folds log2(e): scores come out in log2 domain.
__global__ __launch_bounds__(256) void k_rope(const f16* __restrict__ QKV,
        const float* __restrict__ cosT, const float* __restrict__ sinT,
        const float* __restrict__ bq, const float* __restrict__ bk,
        const float* __restrict__ bv,
        f16* __restrict__ QA, f16* __restrict__ KA, f16* __restrict__ VT) {
    const int tt = blockIdx.x, bh = blockIdx.y;
    const int b = bh >> 4, h = bh & 15;
    const int tid = threadIdx.x;
    const int t_loc = tid >> 2;
    const int f0 = (tid & 3) * 8;
    const int t_abs = tt * 64 + t_loc;
    const size_t tg = (size_t)b * T + t_abs;
    const size_t qkvrow = tg * NQKV;
    constexpr float QSCALE = 0.125f * 1.4426950408889634f;  // 1/8 * log2(e)

    float cs[8], sn[8];
#pragma unroll
    for (int e = 0; e < 8; e++) {
        cs[e] = cosT[t_abs * 32 + f0 + e];
        sn[e] = sinT[t_abs * 32 + f0 + e];
    }
    {
        f16x8 x1 = *(const f16x8*)(QKV + qkvrow + h * 64 + f0);
        f16x8 x2 = *(const f16x8*)(QKV + qkvrow + h * 64 + 32 + f0);
        f16x8 o1, o2;
#pragma unroll
        for (int e = 0; e < 8; e++) {
            float a = (float)x1[e] + bq[h * 64 + f0 + e];
            float c2 = (float)x2[e] + bq[h * 64 + 32 + f0 + e];
            o1[e] = (f16)((a * cs[e] - c2 * sn[e]) * QSCALE);
            o2[e] = (f16)((a * sn[e] + c2 * cs[e]) * QSCALE);
        }
        f16* qa = QA + ((size_t)bh * T + t_abs) * 64;
        *(f16x8*)(qa + f0) = o1;
        *(f16x8*)(qa + 32 + f0) = o2;
    }
    {
        f16x8 x1 = *(const f16x8*)(QKV + qkvrow + DM + h * 64 + f0);
        f16x8 x2 = *(const f16x8*)(QKV + qkvrow + DM + h * 64 + 32 + f0);
        f16x8 o1, o2;
#pragma unroll
        for (int e = 0; e < 8; e++) {
            float a = (float)x1[e] + bk[h * 64 + f0 + e];
            float c2 = (float)x2[e] + bk[h * 64 + 32 + f0 + e];
            o1[e] = (f16)(a * cs[e] - c2 * sn[e]);
            o2[e] = (f16)(a * sn[e] + c2 * cs[e]);
        }
        f16* ka = KA + ((size_t)bh * T + t_abs) * 64;
        *(f16x8*)(ka + f0) = o1;
        *(f16x8*)(ka + 32 + f0) = o2;
    }
    __shared__ f16 sT[64][80];
    {
        int dch = tid & 3;
#pragma unroll
        for (int q2 = 0; q2 < 2; q2++) {
            f16x8 v = *(const f16x8*)(QKV + qkvrow + 2 * DM + h * 64 + dch * 16 + q2 * 8);
#pragma unroll
            for (int e = 0; e < 8; e++) {
                int d = dch * 16 + q2 * 8 + e;
                sT[d][t_loc] = (f16)((float)v[e] + bv[h * 64 + d]);
            }
        }
    }
    __syncthreads();
    {
        int d = tid >> 2, tc = (tid & 3) * 16;
        f16* vt = VT + ((size_t)bh * 64 + d) * T + tt * 64 + tc;
        *(f16x8*)(vt)     = *(const f16x8*)&sT[d][tc];
        *(f16x8*)(vt + 8) = *(const f16x8*)&sT[d][tc + 8];
    }
}

// -------------------------------------------------------- flash attention
static __device__ inline void plswap(unsigned &a, unsigned &b) {
    auto r = __builtin_amdgcn_permlane32_swap(a, b, false, false);
    a = (unsigned)r[0]; b = (unsigned)r[1];
}

static __device__ inline unsigned pk16(float a, float b) {
    union { fp16x2 h; unsigned u; } cv;
    cv.h = __builtin_amdgcn_cvt_pkrtz(a, b);
    return cv.u;
}

// LDS chunk swizzle: uses row bits 0..4 so lanes {r,r+8,r+16,r+24} get
// distinct slots (conflict-free, verified R4: SQ_LDS_BANK_CONFLICT = 0).
static __device__ inline int swz(int r) { return (r ^ (r >> 3)) & 7; }

constexpr int NKVH = 2;          // KV split factor
constexpr int KVLEN = T / NKVH;  // 1024 kv per block

// grid 1024 = kvh*512 + qb*32 + bh; partial (o/l, m, l) -> OP/ML
__global__ __launch_bounds__(256) void k_attn(const f16* __restrict__ QA,
                                              const f16* __restrict__ KA,
                                              const f16* __restrict__ VT,
                                              f16* __restrict__ OP,
                                              float* __restrict__ ML) {
    __shared__ __align__(16) f16 sK[2][64 * 64];
    __shared__ __align__(16) f16 sV[2][64 * 64];
    const int tid = threadIdx.x, w = tid >> 6, l = tid & 63;
    const int lin = blockIdx.x;
    const int bh = lin & 31;            // XCD = lin%8 = bh%8: head-local L2
    const int rest = lin >> 5;
    const int qb = rest & 15, kvh = rest >> 4;
    const int blk = bh * 16 + qb;       // storage index, matches k_merge
    const size_t qbase = (size_t)bh * T * 64;
    const int q0 = qb * 128 + w * 32;
    const int kv0 = kvh * KVLEN;
    const int lq = l & 31, hi = l >> 5;
    const int sw0 = swz(lq);

    f16x8 qf[4];
#pragma unroll
    for (int kc = 0; kc < 4; kc++)
        qf[kc] = *(const f16x8*)(QA + qbase + (size_t)(q0 + lq) * 64 + kc * 16 + hi * 8);

    f32x16 octx[2] = {};
    float mrun = -1e30f, lrun = 0.f;

    const int srow = w * 2;
    const int lr8 = l >> 3, lc8 = l & 7;

#pragma unroll
    for (int j = 0; j < 2; j++) {
        int row = (srow + j) * 8 + lr8;
        int c = lc8 ^ swz(row);
        GLDS16(KA + qbase + (size_t)(kv0 + row) * 64 + c * 8, &sK[0][(srow + j) * 512]);
        GLDS16(VT + qbase + (size_t)row * T + kv0 + c * 8,    &sV[0][(srow + j) * 512]);
    }
    __syncthreads();

    int cur = 0;
    for (int t = 0; t < KVLEN / 64; t++) {
        if (t + 1 < KVLEN / 64) {
            int kv = kv0 + (t + 1) * 64;
#pragma unroll
            for (int j = 0; j < 2; j++) {
                int row = (srow + j) * 8 + lr8;
                int c = lc8 ^ swz(row);
                GLDS16(KA + qbase + (size_t)(kv + row) * 64 + c * 8,
                       &sK[cur ^ 1][(srow + j) * 512]);
                GLDS16(VT + qbase + (size_t)row * T + kv + c * 8,
                       &sV[cur ^ 1][(srow + j) * 512]);
            }
        }

        // ---- QK^T : S^T[k][q] (log2 domain)
        f32x16 st[2] = {};
#pragma unroll
        for (int kc = 0; kc < 4; kc++) {
            int g = kc * 2 + hi;
            f16x8 kf0 = *(const f16x8*)&sK[cur][lq * 64 + (g ^ sw0) * 8];
            f16x8 kf1 = *(const f16x8*)&sK[cur][(32 + lq) * 64 + (g ^ sw0 ^ 4) * 8];
            st[0] = __builtin_amdgcn_mfma_f32_32x32x16_f16(kf0, qf[kc], st[0], 0, 0, 0);
            st[1] = __builtin_amdgcn_mfma_f32_32x32x16_f16(kf1, qf[kc], st[1], 0, 0, 0);
        }

        // ---- tile max (tree) + cross-half
        float tm[16];
#pragma unroll
        for (int r = 0; r < 16; r++) tm[r] = fmaxf(st[0][r], st[1][r]);
#pragma unroll
        for (int s = 8; s >= 1; s >>= 1)
#pragma unroll
            for (int r = 0; r < s; r++) tm[r] = fmaxf(tm[r], tm[r + s]);
        float pm = fmaxf(tm[0], __shfl_xor(tm[0], 32));

        // ---- defer-max (T13): rescale only when max grew by > 8 (log2)
        if (!__all(pm - mrun <= 8.f)) {
            float mn = fmaxf(mrun, pm);
            float sc = exp2f(mrun - mn);
            mrun = mn;
            lrun *= sc;
#pragma unroll
            for (int blkx = 0; blkx < 2; blkx++)
#pragma unroll
                for (int r = 0; r < 16; r++) octx[blkx][r] *= sc;
        }

        // ---- P = exp2(S - m); pack to f16 pairs
#pragma unroll
        for (int blkx = 0; blkx < 2; blkx++)
#pragma unroll
            for (int r = 0; r < 16; r++)
                st[blkx][r] = exp2f(st[blkx][r] - mrun);

        unsigned pw[2][8];
#pragma unroll
        for (int blkx = 0; blkx < 2; blkx++)
#pragma unroll
            for (int j = 0; j < 8; j++) {
                int r = 4 * (j >> 1) + 2 * (j & 1);
                pw[blkx][j] = pk16(st[blkx][r], st[blkx][r + 1]);
            }

        // ---- PV: ctx^T[d][q] += V^T[d][k] * P^T[k][q]
#pragma unroll
        for (int ks = 0; ks < 4; ks++) {
            const int blkx = ks >> 1, h4 = (ks & 1) * 4;
            unsigned m0 = pw[blkx][h4 + 0], m2 = pw[blkx][h4 + 2];
            plswap(m0, m2);
            unsigned m1 = pw[blkx][h4 + 1], m3 = pw[blkx][h4 + 3];
            plswap(m1, m3);
            union { unsigned u[4]; f16x8 v; } pb;
            pb.u[0] = m0; pb.u[1] = m1; pb.u[2] = m2; pb.u[3] = m3;
            int g = ks * 2 + hi;
#pragma unroll
            for (int dblk = 0; dblk < 2; dblk++) {
                f16x8 vf = *(const f16x8*)&sV[cur][(dblk * 32 + lq) * 64 +
                                                   ((g ^ sw0 ^ (dblk * 4)) * 8)];
                octx[dblk] = __builtin_amdgcn_mfma_f32_32x32x16_f16(
                    vf, pb.v, octx[dblk], 0, 0, 0);
            }
        }

        // ---- row-sum (off critical path)
        float s4[4] = {0.f, 0.f, 0.f, 0.f};
#pragma unroll
        for (int blkx = 0; blkx < 2; blkx++)
#pragma unroll
            for (int r = 0; r < 16; r++) s4[r & 3] += st[blkx][r];
        float rs = (s4[0] + s4[1]) + (s4[2] + s4[3]);
        rs += __shfl_xor(rs, 32);
        lrun += rs;

        __syncthreads();
        cur ^= 1;
    }

    // ---- epilogue: store normalized partial (f16) + (m,l)
    float invl = 1.f / lrun;
    unsigned pwout[16];
#pragma unroll
    for (int dblk = 0; dblk < 2; dblk++)
#pragma unroll
        for (int rp = 0; rp < 8; rp++) {
            int r = 2 * rp;
            pwout[dblk * 8 + rp] = pk16(octx[dblk][r] * invl,
                                        octx[dblk][r + 1] * invl);
        }
    f16* ob = OP + (((size_t)(kvh * 512 + blk) * 4 + w) * 64 + l) * 32;
#pragma unroll
    for (int i = 0; i < 4; i++)
        ((uint4*)ob)[i] = *(uint4*)&pwout[i * 4];
    if (hi == 0) {
        float2* mlp = (float2*)ML + ((size_t)(kvh * 512 + blk) * 4 + w) * 32 + lq;
        *mlp = make_float2(mrun, lrun);
    }
}

// ------------------------------------------------------------- KV merge
__global__ __launch_bounds__(256) void k_merge(const f16* __restrict__ OP,
                                               const float* __restrict__ ML,
                                               f16* __restrict__ CTX) {
    const int x = blockIdx.x;           // 512
    const int bh = x & 31, qb = x >> 5;
    const int b = bh >> 4, h = bh & 15;
    const int tid = threadIdx.x, w = tid >> 6, l = tid & 63;
    const int lq = l & 31, hi = l >> 5;
    const int blk = bh * 16 + qb;

    float2 a = ((const float2*)ML)[((size_t)blk * 4 + w) * 32 + lq];
    float2 c = ((const float2*)ML)[((size_t)(512 + blk) * 4 + w) * 32 + lq];
    float m = fmaxf(a.x, c.x);
    float w0 = exp2f(a.x - m) * a.y;
    float w1 = exp2f(c.x - m) * c.y;
    float inv = 1.f / (w0 + w1);
    w0 *= inv; w1 *= inv;

    const uint4* p0 = (const uint4*)(OP + ((size_t)(blk * 4 + w) * 64 + l) * 32);
    const uint4* p1 = (const uint4*)(OP + ((size_t)((512 + blk) * 4 + w) * 64 + l) * 32);
    uint4 u0[4] = { p0[0], p0[1], p0[2], p0[3] };
    uint4 u1[4] = { p1[0], p1[1], p1[2], p1[3] };

    f16* crow = CTX + ((size_t)b * T + qb * 128 + w * 32 + lq) * DM + h * 64;
#pragma unroll
    for (int i = 0; i < 16; i++) {
        union { unsigned u; fp16x2 h; } c0, c1;
        c0.u = ((const unsigned*)u0)[i];
        c1.u = ((const unsigned*)u1)[i];
        float lo = w0 * (float)c0.h[0] + w1 * (float)c1.h[0];
        float hi2 = w0 * (float)c0.h[1] + w1 * (float)c1.h[1];
        int dblk = i >> 3, rp = i & 7;
        int d = dblk * 32 + 8 * (rp >> 1) + 2 * (rp & 1) + 4 * hi;
        *(unsigned*)(crow + d) = pk16(lo, hi2);
    }
}

// ---------------------------------------------------------------- launch
extern "C" void kernel_launch(void* const* d_in, const int* in_sizes, int n_in,
                              void* d_out, int out_size, void* d_ws, size_t ws_size,
                              hipStream_t stream) {
    const float* x  = (const float*)d_in[0];
    const float* Wq = (const float*)d_in[1];
    const float* bq = (const float*)d_in[2];
    const float* Wk = (const float*)d_in[3];
    const float* bk = (const float*)d_in[4];
    const float* Wv = (const float*)d_in[5];
    const float* bv = (const float*)d_in[6];
    const float* Wo = (const float*)d_in[7];
    const float* bo = (const float*)d_in[8];

    char* ws = (char*)d_ws;
    f16*   xh    = (f16*)(ws + 0);
    f16*   ctx   = (f16*)(ws + 0);              // reuses xh region
    f16*   WqkvT = (f16*)(ws + ((size_t)8  << 20));
    f16*   WoT   = (f16*)(ws + ((size_t)14 << 20));
    f16*   QKV   = (f16*)(ws + ((size_t)16 << 20));   // dead after k_rope
    f16*   OP    = (f16*)(ws + ((size_t)16 << 20));   // overlays QKV (16MB)
    float* ML    = (float*)(ws + ((size_t)32 << 20)); // 1MB
    f16*   QA    = (f16*)(ws + ((size_t)40 << 20));
    f16*   KA    = (f16*)(ws + ((size_t)48 << 20));
    f16*   VT    = (f16*)(ws + ((size_t)56 << 20));
    float* cosT  = (float*)(ws + ((size_t)64 << 20));
    float* sinT  = cosT + T * 32;

    k_tables<<<dim3(256), dim3(256), 0, stream>>>(cosT, sinT);
    k_cast_x<<<dim3(2048), dim3(256), 0, stream>>>(x, xh);
    k_wt<<<dim3(32, 32, 4), dim3(32, 8), 0, stream>>>(Wq, Wk, Wv, Wo, WqkvT, WoT);
    k_gemm<false><<<dim3(MT / 128, NQKV / 128), dim3(256), 0, stream>>>(
        xh, WqkvT, (void*)QKV, nullptr, MT, NQKV, DM);
    k_rope<<<dim3(T / 64, B * H), dim3(256), 0, stream>>>(
        QKV, cosT, sinT, bq, bk, bv, QA, KA, VT);
    k_attn<<<dim3(1024), dim3(256), 0, stream>>>(QA, KA, VT, OP, ML);
    k_merge<<<dim3(512), dim3(256), 0, stream>>>(OP, ML, ctx);
    k_gemm<true><<<dim3(MT / 128, DM / 128), dim3(256), 0, stream>>>(
        ctx, WoT, d_out, bo, MT, DM, DM);
}

// Round 6
// 146.085 us; speedup vs baseline: 1.2064x; 1.2064x over previous
//
#include <hip/hip_runtime.h>
#include <hip/hip_bf16.h>
#include <stdint.h>

typedef _Float16 f16;
typedef _Float16 f16x8 __attribute__((ext_vector_type(8)));
typedef __fp16   fp16x2 __attribute__((ext_vector_type(2)));
typedef float    f32x4 __attribute__((ext_vector_type(4)));
typedef float    f32x16 __attribute__((ext_vector_type(16)));

#define GLDS16(g, l) __builtin_amdgcn_global_load_lds(                        \
    (const __attribute__((address_space(1))) void*)(g),                      \
    (__attribute__((address_space(3))) void*)(l), 16, 0, 0)

constexpr int T  = 2048;
constexpr int B  = 2;
constexpr int H  = 16;
constexpr int DM = 1024;
constexpr int MT = B * T;       // 4096 token rows
constexpr int NQKV = 3 * DM;    // 3072

// ---------------------------------------------------------------- tables
__global__ void k_tables(float* __restrict__ cosT, float* __restrict__ sinT) {
    int idx = blockIdx.x * 256 + threadIdx.x;       // T*32 = 65536
    if (idx >= T * 32) return;
    int t = idx >> 5, f = idx & 31;
    float inv = exp2f(-(float)f * 0.41524101186092034f);
    float ang = (float)t * inv;
    cosT[idx] = cosf(ang);
    sinT[idx] = sinf(ang);
}

// ---------------------------------------------------------------- cast x
__global__ void k_cast_x(const float* __restrict__ x, f16* __restrict__ xh) {
    int i = blockIdx.x * 256 + threadIdx.x;         // per 8 elems
    const float4* p = (const float4*)x;
    float4 a = p[i * 2], b = p[i * 2 + 1];
    f16x8 o = { (f16)a.x, (f16)a.y, (f16)a.z, (f16)a.w,
                (f16)b.x, (f16)b.y, (f16)b.z, (f16)b.w };
    ((f16x8*)xh)[i] = o;
}

// ------------------------------------------------- weight cast+transpose
__global__ void k_wt(const float* __restrict__ Wq, const float* __restrict__ Wk,
                     const float* __restrict__ Wv, const float* __restrict__ Wo,
                     f16* __restrict__ WqkvT, f16* __restrict__ WoT) {
    __shared__ float tile[32][33];
    int z = blockIdx.z;
    const float* src = (z == 0) ? Wq : (z == 1) ? Wk : (z == 2) ? Wv : Wo;
    f16* dst = (z < 3) ? (WqkvT + (size_t)z * DM * DM) : WoT;
    int bx = blockIdx.x * 32, by = blockIdx.y * 32;
    int tx = threadIdx.x, ty = threadIdx.y;
#pragma unroll
    for (int j = 0; j < 4; j++)
        tile[ty + j * 8][tx] = src[(size_t)(by + ty + j * 8) * DM + bx + tx];
    __syncthreads();
#pragma unroll
    for (int j = 0; j < 4; j++)
        dst[(size_t)(bx + ty + j * 8) * DM + by + tx] = (f16)tile[tx][ty + j * 8];
}

// ---------------------------------------------------------------- GEMM
template <bool OUTF32>
__global__ __launch_bounds__(256) void k_gemm(const f16* __restrict__ A,
                                              const f16* __restrict__ Bt,
                                              void* __restrict__ Cv,
                                              const float* __restrict__ bias,
                                              int M, int N, int K) {
    __shared__ f16 sA[128 * 64];
    __shared__ f16 sB[128 * 64];
    const int tid = threadIdx.x, w = tid >> 6, l = tid & 63;
    const int m0 = blockIdx.x * 128, n0 = blockIdx.y * 128;
    const int wm = w >> 1, wn = w & 1;
    const int lrow = tid >> 3;
    const int lch  = tid & 7;
    f32x4 acc[4][4] = {};

    for (int kt = 0; kt < K; kt += 64) {
        __syncthreads();
#pragma unroll
        for (int i = 0; i < 4; i++) {
            int row = i * 32 + lrow;
            int c = lch ^ (row & 7);
            GLDS16(A + (size_t)(m0 + row) * K + kt + c * 8, &sA[i * 2048 + w * 512]);
        }
#pragma unroll
        for (int i = 0; i < 4; i++) {
            int row = i * 32 + lrow;
            int c = lch ^ (row & 7);
            GLDS16(Bt + (size_t)(n0 + row) * K + kt + c * 8, &sB[i * 2048 + w * 512]);
        }
        __syncthreads();
#pragma unroll
        for (int ks = 0; ks < 2; ks++) {
            f16x8 af[4], bf[4];
#pragma unroll
            for (int mi = 0; mi < 4; mi++) {
                int row = wm * 64 + mi * 16 + (l & 15);
                int c = (ks * 4 + (l >> 4)) ^ (row & 7);
                af[mi] = *(const f16x8*)&sA[row * 64 + c * 8];
            }
#pragma unroll
            for (int ni = 0; ni < 4; ni++) {
                int row = wn * 64 + ni * 16 + (l & 15);
                int c = (ks * 4 + (l >> 4)) ^ (row & 7);
                bf[ni] = *(const f16x8*)&sB[row * 64 + c * 8];
            }
#pragma unroll
            for (int ni = 0; ni < 4; ni++)
#pragma unroll
                for (int mi = 0; mi < 4; mi++)
                    acc[mi][ni] = __builtin_amdgcn_mfma_f32_16x16x32_f16(
                        af[mi], bf[ni], acc[mi][ni], 0, 0, 0);
        }
    }
    const int rb = m0 + wm * 64 + ((l >> 4) << 2);
    const int cb = n0 + wn * 64 + (l & 15);
#pragma unroll
    for (int ni = 0; ni < 4; ni++) {
        int col = cb + ni * 16;
        float bz = bias ? bias[col] : 0.f;
#pragma unroll
        for (int mi = 0; mi < 4; mi++) {
#pragma unroll
            for (int r = 0; r < 4; r++) {
                int row = rb + mi * 16 + r;
                float v = acc[mi][ni][r] + bz;
                if (OUTF32) ((float*)Cv)[(size_t)row * N + col] = v;
                else        ((f16*)Cv)[(size_t)row * N + col] = (f16)v;
            }
        }
    }
}

// --------------------------------------------- RoPE + bias + head permute
// Q pre-scale folds log2(e): scores come out in log2 domain.
__global__ __launch_bounds__(256) void k_rope(const f16* __restrict__ QKV,
        const float* __restrict__ cosT, const float* __restrict__ sinT,
        const float* __restrict__ bq, const float* __restrict__ bk,
        const float* __restrict__ bv,
        f16* __restrict__ QA, f16* __restrict__ KA, f16* __restrict__ VT) {
    const int tt = blockIdx.x, bh = blockIdx.y;
    const int b = bh >> 4, h = bh & 15;
    const int tid = threadIdx.x;
    const int t_loc = tid >> 2;
    const int f0 = (tid & 3) * 8;
    const int t_abs = tt * 64 + t_loc;
    const size_t tg = (size_t)b * T + t_abs;
    const size_t qkvrow = tg * NQKV;
    constexpr float QSCALE = 0.125f * 1.4426950408889634f;  // 1/8 * log2(e)

    float cs[8], sn[8];
#pragma unroll
    for (int e = 0; e < 8; e++) {
        cs[e] = cosT[t_abs * 32 + f0 + e];
        sn[e] = sinT[t_abs * 32 + f0 + e];
    }
    {
        f16x8 x1 = *(const f16x8*)(QKV + qkvrow + h * 64 + f0);
        f16x8 x2 = *(const f16x8*)(QKV + qkvrow + h * 64 + 32 + f0);
        f16x8 o1, o2;
#pragma unroll
        for (int e = 0; e < 8; e++) {
            float a = (float)x1[e] + bq[h * 64 + f0 + e];
            float c2 = (float)x2[e] + bq[h * 64 + 32 + f0 + e];
            o1[e] = (f16)((a * cs[e] - c2 * sn[e]) * QSCALE);
            o2[e] = (f16)((a * sn[e] + c2 * cs[e]) * QSCALE);
        }
        f16* qa = QA + ((size_t)bh * T + t_abs) * 64;
        *(f16x8*)(qa + f0) = o1;
        *(f16x8*)(qa + 32 + f0) = o2;
    }
    {
        f16x8 x1 = *(const f16x8*)(QKV + qkvrow + DM + h * 64 + f0);
        f16x8 x2 = *(const f16x8*)(QKV + qkvrow + DM + h * 64 + 32 + f0);
        f16x8 o1, o2;
#pragma unroll
        for (int e = 0; e < 8; e++) {
            float a = (float)x1[e] + bk[h * 64 + f0 + e];
            float c2 = (float)x2[e] + bk[h * 64 + 32 + f0 + e];
            o1[e] = (f16)(a * cs[e] - c2 * sn[e]);
            o2[e] = (f16)(a * sn[e] + c2 * cs[e]);
        }
        f16* ka = KA + ((size_t)bh * T + t_abs) * 64;
        *(f16x8*)(ka + f0) = o1;
        *(f16x8*)(ka + 32 + f0) = o2;
    }
    __shared__ f16 sT[64][80];
    {
        int dch = tid & 3;
#pragma unroll
        for (int q2 = 0; q2 < 2; q2++) {
            f16x8 v = *(const f16x8*)(QKV + qkvrow + 2 * DM + h * 64 + dch * 16 + q2 * 8);
#pragma unroll
            for (int e = 0; e < 8; e++) {
                int d = dch * 16 + q2 * 8 + e;
                sT[d][t_loc] = (f16)((float)v[e] + bv[h * 64 + d]);
            }
        }
    }
    __syncthreads();
    {
        int d = tid >> 2, tc = (tid & 3) * 16;
        f16* vt = VT + ((size_t)bh * 64 + d) * T + tt * 64 + tc;
        *(f16x8*)(vt)     = *(const f16x8*)&sT[d][tc];
        *(f16x8*)(vt + 8) = *(const f16x8*)&sT[d][tc + 8];
    }
}

// -------------------------------------------------------- flash attention
static __device__ inline void plswap(unsigned &a, unsigned &b) {
    auto r = __builtin_amdgcn_permlane32_swap(a, b, false, false);
    a = (unsigned)r[0]; b = (unsigned)r[1];
}

static __device__ inline unsigned pk16(float a, float b) {
    union { fp16x2 h; unsigned u; } cv;
    cv.h = __builtin_amdgcn_cvt_pkrtz(a, b);
    return cv.u;
}

// native v_exp_f32 (exp2): avoids ocml exp2f's range-fixup VALU bloat
static __device__ inline float ex2(float x) {
#if __has_builtin(__builtin_amdgcn_exp2f)
    return __builtin_amdgcn_exp2f(x);
#else
    float r;
    asm volatile("v_exp_f32 %0, %1\n\ts_nop 1" : "=v"(r) : "v"(x));
    return r;
#endif
}

// cross-half (lane vs lane^32) combine via one permlane32_swap:
// r0+r1 (or fmax(r0,r1)) equals own+partner on BOTH halves.
static __device__ inline float xhalf_sum(float x) {
    union { float f; unsigned u; } a = { x };
    auto r = __builtin_amdgcn_permlane32_swap(a.u, a.u, false, false);
    union { unsigned u; float f; } p0 = { (unsigned)r[0] }, p1 = { (unsigned)r[1] };
    return p0.f + p1.f;
}
static __device__ inline float xhalf_max(float x) {
    union { float f; unsigned u; } a = { x };
    auto r = __builtin_amdgcn_permlane32_swap(a.u, a.u, false, false);
    union { unsigned u; float f; } p0 = { (unsigned)r[0] }, p1 = { (unsigned)r[1] };
    return fmaxf(p0.f, p1.f);
}

// LDS chunk swizzle (conflict-free, verified: SQ_LDS_BANK_CONFLICT = 0)
static __device__ inline int swz(int r) { return (r ^ (r >> 3)) & 7; }

constexpr int NT = T / 64;  // 32 kv tiles

__global__ __launch_bounds__(256) void k_attn(const f16* __restrict__ QA,
                                              const f16* __restrict__ KA,
                                              const f16* __restrict__ VT,
                                              f16* __restrict__ CTX) {
    __shared__ __align__(16) f16 sK[2][64 * 64];
    __shared__ __align__(16) f16 sV[2][64 * 64];
    const int tid = threadIdx.x, w = tid >> 6, l = tid & 63;
    const int lin = blockIdx.x;                 // 512 blocks
    const int bh = lin & 31, qb = lin >> 5;     // XCD = bh%8: head-local L2
    const int b = bh >> 4, h = bh & 15;
    const size_t qbase = (size_t)bh * T * 64;
    const int q0 = qb * 128 + w * 32;
    const int lq = l & 31, hi = l >> 5;
    const int sw0 = swz(lq);

    // Q as B-operand fragments
    f16x8 qf[4];
#pragma unroll
    for (int kc = 0; kc < 4; kc++)
        qf[kc] = *(const f16x8*)(QA + qbase + (size_t)(q0 + lq) * 64 + kc * 16 + hi * 8);

    // hoisted LDS read indices (shared by QK^T kf and PV vf reads)
    int idx0[4], idx1[4];
#pragma unroll
    for (int kc = 0; kc < 4; kc++) {
        int g = kc * 2 + hi;
        idx0[kc] = lq * 64 + ((g ^ sw0) * 8);
        idx1[kc] = (32 + lq) * 64 + ((g ^ sw0 ^ 4) * 8);
    }

    f32x16 octx0 = {}, octx1 = {};
    float mrun = -1e30f, lrun = 0.f;

    // hoisted staging pointers (wave w stages rows w*16..w*16+15)
    const int srow = w * 2;
    const int lr8 = l >> 3, lc8 = l & 7;
    const int row0 = srow * 8 + lr8, row1 = row0 + 8;
    const int c0 = lc8 ^ swz(row0), c1 = lc8 ^ swz(row1);
    const f16* gK0 = KA + qbase + (size_t)row0 * 64 + c0 * 8;
    const f16* gK1 = KA + qbase + (size_t)row1 * 64 + c1 * 8;
    const f16* gV0 = VT + qbase + (size_t)row0 * T + c0 * 8;
    const f16* gV1 = VT + qbase + (size_t)row1 * T + c1 * 8;

    // prologue: stage tile 0 into buf 0
    GLDS16(gK0, &sK[0][srow * 512]);
    GLDS16(gK1, &sK[0][(srow + 1) * 512]);
    GLDS16(gV0, &sV[0][srow * 512]);
    GLDS16(gV1, &sV[0][(srow + 1) * 512]);
    gK0 += 4096; gK1 += 4096; gV0 += 64; gV1 += 64;
    __syncthreads();

#define ATT_TILE(CUR, TN)                                                     \
    {                                                                         \
        if ((TN) < NT) {                                                      \
            GLDS16(gK0, &sK[CUR ^ 1][srow * 512]);                            \
            GLDS16(gK1, &sK[CUR ^ 1][(srow + 1) * 512]);                      \
            GLDS16(gV0, &sV[CUR ^ 1][srow * 512]);                            \
            GLDS16(gV1, &sV[CUR ^ 1][(srow + 1) * 512]);                      \
            gK0 += 4096; gK1 += 4096; gV0 += 64; gV1 += 64;                   \
        }                                                                     \
        f32x16 st0 = {}, st1 = {};                                            \
        _Pragma("unroll")                                                     \
        for (int kc = 0; kc < 4; kc++) {                                      \
            f16x8 kf0 = *(const f16x8*)&sK[CUR][idx0[kc]];                    \
            f16x8 kf1 = *(const f16x8*)&sK[CUR][idx1[kc]];                    \
            st0 = __builtin_amdgcn_mfma_f32_32x32x16_f16(kf0, qf[kc], st0, 0, 0, 0); \
            st1 = __builtin_amdgcn_mfma_f32_32x32x16_f16(kf1, qf[kc], st1, 0, 0, 0); \
        }                                                                     \
        float tm[16];                                                         \
        _Pragma("unroll")                                                     \
        for (int r = 0; r < 16; r++) tm[r] = fmaxf(st0[r], st1[r]);           \
        _Pragma("unroll")                                                     \
        for (int s = 8; s >= 1; s >>= 1) {                                    \
            _Pragma("unroll")                                                 \
            for (int r = 0; r < s; r++) tm[r] = fmaxf(tm[r], tm[r + s]);      \
        }                                                                     \
        float pm = xhalf_max(tm[0]);                                          \
        if (!__all(pm - mrun <= 8.f)) {                                       \
            float mn = fmaxf(mrun, pm);                                       \
            float sc = ex2(mrun - mn);                                        \
            mrun = mn; lrun *= sc;                                            \
            _Pragma("unroll")                                                 \
            for (int r = 0; r < 16; r++) { octx0[r] *= sc; octx1[r] *= sc; }  \
        }                                                                     \
        _Pragma("unroll")                                                     \
        for (int r = 0; r < 16; r++) {                                        \
            st0[r] = ex2(st0[r] - mrun);                                      \
            st1[r] = ex2(st1[r] - mrun);                                      \
        }                                                                     \
        unsigned pw0[8], pw1[8];                                              \
        _Pragma("unroll")                                                     \
        for (int j = 0; j < 8; j++) {                                         \
            int r = 4 * (j >> 1) + 2 * (j & 1);                               \
            pw0[j] = pk16(st0[r], st0[r + 1]);                                \
            pw1[j] = pk16(st1[r], st1[r + 1]);                                \
        }                                                                     \
        _Pragma("unroll")                                                     \
        for (int ks = 0; ks < 4; ks++) {                                      \
            unsigned* pwx = (ks < 2) ? pw0 : pw1;                             \
            const int h4 = (ks & 1) * 4;                                      \
            unsigned m0 = pwx[h4 + 0], m2 = pwx[h4 + 2];                      \
            plswap(m0, m2);                                                   \
            unsigned m1 = pwx[h4 + 1], m3 = pwx[h4 + 3];                      \
            plswap(m1, m3);                                                   \
            union { unsigned u[4]; f16x8 v; } pb;                             \
            pb.u[0] = m0; pb.u[1] = m1; pb.u[2] = m2; pb.u[3] = m3;           \
            f16x8 vf0 = *(const f16x8*)&sV[CUR][idx0[ks]];                    \
            f16x8 vf1 = *(const f16x8*)&sV[CUR][idx1[ks]];                    \
            octx0 = __builtin_amdgcn_mfma_f32_32x32x16_f16(vf0, pb.v, octx0, 0, 0, 0); \
            octx1 = __builtin_amdgcn_mfma_f32_32x32x16_f16(vf1, pb.v, octx1, 0, 0, 0); \
        }                                                                     \
        float s4a = 0.f, s4b = 0.f, s4c = 0.f, s4d = 0.f;                     \
        _Pragma("unroll")                                                     \
        for (int r = 0; r < 16; r += 4) {                                     \
            s4a += st0[r] + st1[r];     s4b += st0[r + 1] + st1[r + 1];       \
            s4c += st0[r + 2] + st1[r + 2]; s4d += st0[r + 3] + st1[r + 3];   \
        }                                                                     \
        lrun += xhalf_sum((s4a + s4b) + (s4c + s4d));                         \
        __syncthreads();                                                      \
    }

    for (int t = 0; t < NT; t += 2) {
        ATT_TILE(0, t + 1)
        ATT_TILE(1, t + 2)
    }
#undef ATT_TILE

    // ---- epilogue: ctx^T / l -> CTX[b*T+q][h*64+d] (f16, paired stores)
    float inv = 1.f / lrun;
    f16* crow = CTX + ((size_t)b * T + q0 + lq) * DM + h * 64;
#pragma unroll
    for (int rp = 0; rp < 8; rp++) {
        int r = 2 * rp;
        int d = 8 * (rp >> 1) + 2 * (rp & 1) + 4 * hi;
        *(unsigned*)(crow + d)      = pk16(octx0[r] * inv, octx0[r + 1] * inv);
        *(unsigned*)(crow + 32 + d) = pk16(octx1[r] * inv, octx1[r + 1] * inv);
    }
}

// ---------------------------------------------------------------- launch
extern "C" void kernel_launch(void* const* d_in, const int* in_sizes, int n_in,
                              void* d_out, int out_size, void* d_ws, size_t ws_size,
                              hipStream_t stream) {
    const float* x  = (const float*)d_in[0];
    const float* Wq = (const float*)d_in[1];
    const float* bq = (const float*)d_in[2];
    const float* Wk = (const float*)d_in[3];
    const float* bk = (const float*)d_in[4];
    const float* Wv = (const float*)d_in[5];
    const float* bv = (const float*)d_in[6];
    const float* Wo = (const float*)d_in[7];
    const float* bo = (const float*)d_in[8];

    char* ws = (char*)d_ws;
    f16*   xh    = (f16*)(ws + 0);
    f16*   ctx   = (f16*)(ws + 0);              // reuses xh region
    f16*   WqkvT = (f16*)(ws + ((size_t)8  << 20));
    f16*   WoT   = (f16*)(ws + ((size_t)14 << 20));
    f16*   QKV   = (f16*)(ws + ((size_t)16 << 20));
    f16*   QA    = (f16*)(ws + ((size_t)40 << 20));
    f16*   KA    = (f16*)(ws + ((size_t)48 << 20));
    f16*   VT    = (f16*)(ws + ((size_t)56 << 20));
    float* cosT  = (float*)(ws + ((size_t)64 << 20));
    float* sinT  = cosT + T * 32;

    k_tables<<<dim3(256), dim3(256), 0, stream>>>(cosT, sinT);
    k_cast_x<<<dim3(2048), dim3(256), 0, stream>>>(x, xh);
    k_wt<<<dim3(32, 32, 4), dim3(32, 8), 0, stream>>>(Wq, Wk, Wv, Wo, WqkvT, WoT);
    k_gemm<false><<<dim3(MT / 128, NQKV / 128), dim3(256), 0, stream>>>(
        xh, WqkvT, (void*)QKV, nullptr, MT, NQKV, DM);
    k_rope<<<dim3(T / 64, B * H), dim3(256), 0, stream>>>(
        QKV, cosT, sinT, bq, bk, bv, QA, KA, VT);
    k_attn<<<dim3(512), dim3(256), 0, stream>>>(QA, KA, VT, ctx);
    k_gemm<true><<<dim3(MT / 128, DM / 128), dim3(256), 0, stream>>>(
        ctx, WoT, d_out, bo, MT, DM, DM);
}